// Round 6
// baseline (14369.611 us; speedup 1.0000x reference)
//
#include <hip/hip_runtime.h>
#include <hip/hip_bf16.h>
#include <hip/hip_cooperative_groups.h>

namespace cg = cooperative_groups;

#define BB   256
#define TCAP 51
#define TT   50
#define VV   10000
#define WDIM 512
#define HH   512
#define ICC  2048
#define G3H  1536

typedef __attribute__((ext_vector_type(8))) short short8v;
typedef __attribute__((ext_vector_type(4))) float f32x4;

__device__ __forceinline__ unsigned short f2bf(float f) {
    unsigned u; __builtin_memcpy(&u, &f, 4);
    unsigned r = (u + 0x7FFFu + ((u >> 16) & 1u)) >> 16;   // RNE
    return (unsigned short)r;
}

__device__ __forceinline__ short8v cvt8(float4 a, float4 b) {
    union { unsigned short u[8]; short8v v; } o;
    o.u[0] = f2bf(a.x); o.u[1] = f2bf(a.y); o.u[2] = f2bf(a.z); o.u[3] = f2bf(a.w);
    o.u[4] = f2bf(b.x); o.u[5] = f2bf(b.y); o.u[6] = f2bf(b.z); o.u[7] = f2bf(b.w);
    return o.v;
}

__device__ __forceinline__ float sigm(float x) { return 1.f / (1.f + expf(-x)); }
__device__ __forceinline__ float dot4(float4 a, float4 b) {
    return a.x * b.x + a.y * b.y + a.z * b.z + a.w * b.w;
}

// ---------------- sort (stable, descending) + tail outputs (f32) ----------------
__global__ void sort_kernel(const int* __restrict__ cap_lens, const int* __restrict__ captions,
                            int* __restrict__ order_ws, int* __restrict__ len_ws,
                            int* __restrict__ caps_ws, float* __restrict__ out,
                            size_t predN) {
    __shared__ int s_order[BB];
    int i = threadIdx.x;
    int li = cap_lens[i];
    int rank = 0;
    for (int j = 0; j < BB; ++j) {
        int lj = cap_lens[j];
        rank += (lj > li) || (lj == li && j < i);
    }
    s_order[rank] = i;
    __syncthreads();
    int src = s_order[i];
    order_ws[i] = src;
    int len = cap_lens[src] - 1;
    len_ws[i] = len;
    for (int t = 0; t < TCAP; ++t) {
        int c = captions[src * TCAP + t];
        caps_ws[i * TCAP + t] = c;
        out[predN + (size_t)i * TCAP + t] = (float)c;
    }
    out[predN + (size_t)BB * TCAP + i]      = (float)len;
    out[predN + (size_t)BB * TCAP + BB + i] = (float)src;
}

// ---------------- gather image rows (sorted) -> bf16 ----------------
__global__ void gather_imgb(const float* __restrict__ image_code, const int* __restrict__ order_ws,
                            unsigned short* __restrict__ imgb) {
    int i = blockIdx.x * 256 + threadIdx.x;       // 65536 total, 8 elems each
    int p = i >> 8, c8 = (i & 255) << 3;
    const float* s = image_code + (size_t)order_ws[p] * ICC + c8;
    float4 v0 = *(const float4*)s, v1 = *(const float4*)(s + 4);
    *(short8v*)&imgb[(size_t)p * ICC + c8] = cvt8(v0, v1);
}

// ---------------- strided f32 -> bf16 matrix convert ----------------
__global__ void cvt_mat(const float* __restrict__ src, int src_ld, int col_off,
                        unsigned short* __restrict__ dst, int cols, int n8) {
    int i = blockIdx.x * 256 + threadIdx.x;
    if (i < n8) {
        int cpr = cols >> 3;
        int row = i / cpr, c8 = (i - row * cpr) << 3;
        const float* s = src + (size_t)row * src_ld + col_off + c8;
        float4 v0 = *(const float4*)s, v1 = *(const float4*)(s + 4);
        *(short8v*)&dst[(size_t)row * cols + c8] = cvt8(v0, v1);
    }
}

#define FCP 8

// ---------------- front GEMM: [256 x 2560] = imgb @ wcomb^T -> h0, h1, gi_img ----------------
__global__ __launch_bounds__(256) void gemm_front(
    const unsigned short* __restrict__ imgb,    // [256][2048]
    const unsigned short* __restrict__ wcomb,   // [2560][2048]
    const float* __restrict__ init_b,           // [1024]
    const float* __restrict__ b_ih0,            // [1536]
    float* __restrict__ h0, float* __restrict__ h1, float* __restrict__ gi_img) {
    const int p0 = blockIdx.y * 64;
    const int c0 = blockIdx.x * 64;
    const int tid = threadIdx.x;
    __shared__ unsigned short As[64][64 + FCP], Bs[64][64 + FCP];
    const int lane = tid & 63, w = tid >> 6;
    f32x4 acc[4] = {};
    for (int k0 = 0; k0 < ICC; k0 += 64) {
#pragma unroll
        for (int v = 0; v < 2; ++v) {
            int e = tid + v * 256;
            int rr = e >> 3, kk = (e & 7) * 8;
            *(short8v*)&As[rr][kk] = *(const short8v*)&imgb[(size_t)(p0 + rr) * ICC + k0 + kk];
            *(short8v*)&Bs[rr][kk] = *(const short8v*)&wcomb[(size_t)(c0 + rr) * ICC + k0 + kk];
        }
        __syncthreads();
#pragma unroll
        for (int ks = 0; ks < 64; ks += 32) {
            short8v a = *(const short8v*)&As[w * 16 + (lane & 15)][ks + (lane >> 4) * 8];
#pragma unroll
            for (int n = 0; n < 4; ++n) {
                short8v b = *(const short8v*)&Bs[n * 16 + (lane & 15)][ks + (lane >> 4) * 8];
                acc[n] = __builtin_amdgcn_mfma_f32_16x16x32_bf16(a, b, acc[n], 0, 0, 0);
            }
        }
        __syncthreads();
    }
#pragma unroll
    for (int n = 0; n < 4; ++n) {
        int cc = c0 + n * 16 + (lane & 15);
#pragma unroll
        for (int r = 0; r < 4; ++r) {
            int pr = p0 + w * 16 + (lane >> 4) * 4 + r;
            float v = acc[n][r];
            if (cc < 1024) {
                v += init_b[cc];
                if (cc < 512) h0[(size_t)pr * HH + cc] = v;
                else          h1[(size_t)pr * HH + (cc - 512)] = v;
            } else {
                gi_img[(size_t)pr * G3H + (cc - 1024)] = v + b_ih0[cc - 1024];
            }
        }
    }
}

// ---------------- gi GEMM: gi_all[t,p,:] = emb_bf16 @ w_ihe^T + gi_img ----------------
__global__ __launch_bounds__(256) void gemm_giemb(
    const unsigned short* __restrict__ embb,    // [VV][512]
    const unsigned short* __restrict__ wihe,    // [1536][512]
    const float* __restrict__ gi_img,           // [256][1536]
    const int* __restrict__ caps_ws, const int* __restrict__ len_ws,
    float* __restrict__ gi_all) {
    const int r0 = blockIdx.y * 64;
    const int t = r0 >> 8, p0 = r0 & 255;
    if (len_ws[p0] <= t) return;
    const int c0 = blockIdx.x * 64;
    const int tid = threadIdx.x;
    __shared__ unsigned short As[64][64 + FCP], Bs[64][64 + FCP];
    __shared__ int s_arow[64];
    if (tid < 64) s_arow[tid] = caps_ws[(p0 + tid) * TCAP + t];
    __syncthreads();
    const int lane = tid & 63, w = tid >> 6;
    f32x4 acc[4] = {};
    for (int k0 = 0; k0 < WDIM; k0 += 64) {
#pragma unroll
        for (int v = 0; v < 2; ++v) {
            int e = tid + v * 256;
            int rr = e >> 3, kk = (e & 7) * 8;
            *(short8v*)&As[rr][kk] = *(const short8v*)&embb[(size_t)s_arow[rr] * WDIM + k0 + kk];
            *(short8v*)&Bs[rr][kk] = *(const short8v*)&wihe[(size_t)(c0 + rr) * WDIM + k0 + kk];
        }
        __syncthreads();
#pragma unroll
        for (int ks = 0; ks < 64; ks += 32) {
            short8v a = *(const short8v*)&As[w * 16 + (lane & 15)][ks + (lane >> 4) * 8];
#pragma unroll
            for (int n = 0; n < 4; ++n) {
                short8v b = *(const short8v*)&Bs[n * 16 + (lane & 15)][ks + (lane >> 4) * 8];
                acc[n] = __builtin_amdgcn_mfma_f32_16x16x32_bf16(a, b, acc[n], 0, 0, 0);
            }
        }
        __syncthreads();
    }
#pragma unroll
    for (int n = 0; n < 4; ++n) {
        int cc = c0 + n * 16 + (lane & 15);
#pragma unroll
        for (int r = 0; r < 4; ++r) {
            int pr = p0 + w * 16 + (lane >> 4) * 4 + r;
            if (t < len_ws[pr])
                gi_all[((size_t)t * BB + pr) * G3H + cc] = acc[n][r] + gi_img[(size_t)pr * G3H + cc];
        }
    }
}

// ---------------- predictions = H1(bf16) @ fc_wb^T + fc_b via MFMA, masked, f32 ----------------
__global__ __launch_bounds__(256) void gemm_fc_mfma(
    const unsigned short* __restrict__ h1x,   // [TT*BB][512] bf16 bits (t-major rows)
    const unsigned short* __restrict__ fcwb,  // [VV][512] bf16 bits
    const float* __restrict__ fc_b,
    const int* __restrict__ len_ws,
    float* __restrict__ out) {
    const int r0 = blockIdx.y * 64;
    const int t = r0 >> 8, p0 = r0 & 255;
    const int c0 = blockIdx.x * 64;
    const int tid = threadIdx.x;
    if (len_ws[p0] <= t) {
        for (int e = tid; e < 64 * 16; e += 256) {
            int rl = e >> 4, c = c0 + (e & 15) * 4;
            if (c < VV) {
                float4 z = {0.f, 0.f, 0.f, 0.f};
                *(float4*)&out[((size_t)(p0 + rl) * TT + t) * VV + c] = z;
            }
        }
        return;
    }
    __shared__ unsigned short As[64][64 + FCP];
    __shared__ unsigned short Bs[64][64 + FCP];
    const int lane = tid & 63, w = tid >> 6;
    f32x4 acc[4] = {};
    for (int k0 = 0; k0 < HH; k0 += 64) {
#pragma unroll
        for (int v = 0; v < 2; ++v) {
            int e = tid + v * 256;
            int rr = e >> 3, kk = (e & 7) * 8;
            *(short8v*)&As[rr][kk] =
                *(const short8v*)&h1x[((size_t)(t * BB + p0 + rr)) * HH + k0 + kk];
            int bc = c0 + rr;
            short8v bv = {};
            if (bc < VV) bv = *(const short8v*)&fcwb[(size_t)bc * HH + k0 + kk];
            *(short8v*)&Bs[rr][kk] = bv;
        }
        __syncthreads();
#pragma unroll
        for (int ks = 0; ks < 64; ks += 32) {
            short8v a = *(const short8v*)&As[w * 16 + (lane & 15)][ks + (lane >> 4) * 8];
#pragma unroll
            for (int n = 0; n < 4; ++n) {
                short8v b = *(const short8v*)&Bs[n * 16 + (lane & 15)][ks + (lane >> 4) * 8];
                acc[n] = __builtin_amdgcn_mfma_f32_16x16x32_bf16(a, b, acc[n], 0, 0, 0);
            }
        }
        __syncthreads();
    }
#pragma unroll
    for (int n = 0; n < 4; ++n) {
        int c = c0 + n * 16 + (lane & 15);
        if (c < VV) {
            float bias = fc_b[c];
#pragma unroll
            for (int r = 0; r < 4; ++r) {
                int pr = p0 + w * 16 + (lane >> 4) * 4 + r;
                bool act = (t < len_ws[pr]);
                out[((size_t)pr * TT + t) * VV + c] = act ? (acc[n][r] + bias) : 0.f;
            }
        }
    }
}

// ---------------- persistent cooperative GRU: 50 steps x 2 layers, grid.sync between ----------
#define HPAD 516

__global__ __launch_bounds__(128) void gru_persist(
    const float* __restrict__ gi_all,
    float* __restrict__ h0a, float* __restrict__ h0b,
    float* __restrict__ h1a, float* __restrict__ h1b,
    unsigned short* __restrict__ h1x,
    const float* __restrict__ w_hh0, const float* __restrict__ b_hh0,
    const float* __restrict__ w_ih1, const float* __restrict__ b_ih1,
    const float* __restrict__ w_hh1, const float* __restrict__ b_hh1,
    const int* __restrict__ len_ws) {
    cg::grid_group grid = cg::this_grid();
    const int c0 = blockIdx.x * 32;    // 16 col-blocks
    const int p0 = blockIdx.y * 8;     // 32 row-blocks
    extern __shared__ float smem[];
    float* s_h = smem;                 // 8*HPAD
    float* s_x = smem + 8 * HPAD;      // 8*HPAD
    const int rl = threadIdx.x & 7;
    const int cp = threadIdx.x >> 3;
    const int c = c0 + cp * 2;
    const int p = p0 + rl;
    const int mylen = len_ws[p];
    const int blklen = len_ws[p0];     // sorted desc -> max of tile
    float* h0c = h0a; float* h0n = h0b;
    float* h1c = h1a; float* h1n = h1b;
    const float4* whr0 = (const float4*)(w_hh0 + (size_t)c * HH);
    const float4* whz0 = (const float4*)(w_hh0 + (size_t)(HH + c) * HH);
    const float4* whn0 = (const float4*)(w_hh0 + (size_t)(2 * HH + c) * HH);
    const float4* whr1 = (const float4*)(w_hh1 + (size_t)c * HH);
    const float4* whz1 = (const float4*)(w_hh1 + (size_t)(HH + c) * HH);
    const float4* whn1 = (const float4*)(w_hh1 + (size_t)(2 * HH + c) * HH);
    const float4* wir1 = (const float4*)(w_ih1 + (size_t)c * HH);
    const float4* wiz1 = (const float4*)(w_ih1 + (size_t)(HH + c) * HH);
    const float4* win1 = (const float4*)(w_ih1 + (size_t)(2 * HH + c) * HH);

    for (int t = 0; t < TT; ++t) {
        // ---------------- layer 0 ----------------
        if (blklen > t) {
            for (int e = threadIdx.x; e < 8 * HH; e += 128) {
                int rw = e >> 9, k = e & 511;
                s_h[rw * HPAD + k] = h0c[(size_t)(p0 + rw) * HH + k];
            }
            __syncthreads();
            float ar0 = 0, ar1 = 0, az0 = 0, az1 = 0, an0 = 0, an1 = 0;
            const float4* hp = (const float4*)(s_h + rl * HPAD);
            for (int k4 = 0; k4 < HH / 4; ++k4) {
                float4 h = hp[k4];
                ar0 += dot4(h, whr0[k4]); ar1 += dot4(h, whr0[k4 + 128]);
                az0 += dot4(h, whz0[k4]); az1 += dot4(h, whz0[k4 + 128]);
                an0 += dot4(h, whn0[k4]); an1 += dot4(h, whn0[k4 + 128]);
            }
            if (t < mylen) {
                const float* gi = gi_all + ((size_t)t * BB + p) * G3H;
#pragma unroll
                for (int u = 0; u < 2; ++u) {
                    int cc = c + u;
                    float r = sigm(gi[cc] + (u ? ar1 : ar0) + b_hh0[cc]);
                    float z = sigm(gi[HH + cc] + (u ? az1 : az0) + b_hh0[HH + cc]);
                    float hn = (u ? an1 : an0) + b_hh0[2 * HH + cc];
                    float n = tanhf(gi[2 * HH + cc] + r * hn);
                    float hold = s_h[rl * HPAD + cc];
                    h0n[(size_t)p * HH + cc] = (1.f - z) * n + z * hold;
                }
            }
        }
        __threadfence();
        grid.sync();
        // ---------------- layer 1 ----------------
        if (blklen > t) {
            for (int e = threadIdx.x; e < 8 * HH; e += 128) {
                int rw = e >> 9, k = e & 511;
                s_h[rw * HPAD + k] = h1c[(size_t)(p0 + rw) * HH + k];
                s_x[rw * HPAD + k] = h0n[(size_t)(p0 + rw) * HH + k];
            }
            __syncthreads();
            float ar0 = 0, ar1 = 0, az0 = 0, az1 = 0, an0 = 0, an1 = 0;
            float xr0 = 0, xr1 = 0, xz0 = 0, xz1 = 0, xn0 = 0, xn1 = 0;
            const float4* hp = (const float4*)(s_h + rl * HPAD);
            const float4* xp = (const float4*)(s_x + rl * HPAD);
            for (int k4 = 0; k4 < HH / 4; ++k4) {
                float4 h = hp[k4];
                ar0 += dot4(h, whr1[k4]); ar1 += dot4(h, whr1[k4 + 128]);
                az0 += dot4(h, whz1[k4]); az1 += dot4(h, whz1[k4 + 128]);
                an0 += dot4(h, whn1[k4]); an1 += dot4(h, whn1[k4 + 128]);
                float4 x = xp[k4];
                xr0 += dot4(x, wir1[k4]); xr1 += dot4(x, wir1[k4 + 128]);
                xz0 += dot4(x, wiz1[k4]); xz1 += dot4(x, wiz1[k4 + 128]);
                xn0 += dot4(x, win1[k4]); xn1 += dot4(x, win1[k4 + 128]);
            }
            if (t < mylen) {
#pragma unroll
                for (int u = 0; u < 2; ++u) {
                    int cc = c + u;
                    float gr = (u ? xr1 : xr0) + b_ih1[cc];
                    float gz = (u ? xz1 : xz0) + b_ih1[HH + cc];
                    float gn = (u ? xn1 : xn0) + b_ih1[2 * HH + cc];
                    float r = sigm(gr + (u ? ar1 : ar0) + b_hh1[cc]);
                    float z = sigm(gz + (u ? az1 : az0) + b_hh1[HH + cc]);
                    float hn = (u ? an1 : an0) + b_hh1[2 * HH + cc];
                    float n = tanhf(gn + r * hn);
                    float hold = s_h[rl * HPAD + cc];
                    float hnew = (1.f - z) * n + z * hold;
                    h1n[(size_t)p * HH + cc] = hnew;
                    h1x[((size_t)t * BB + p) * HH + cc] = f2bf(hnew);
                }
            }
        }
        __threadfence();
        grid.sync();
        { float* tmp = h0c; h0c = h0n; h0n = tmp; tmp = h1c; h1c = h1n; h1n = tmp; }
    }
}

// ---------------- launch ----------------
extern "C" void kernel_launch(void* const* d_in, const int* in_sizes, int n_in,
                              void* d_out, int out_size, void* d_ws, size_t ws_size,
                              hipStream_t stream) {
    const float* image_code = (const float*)d_in[0];
    const int*   captions   = (const int*)d_in[1];
    const int*   cap_lens   = (const int*)d_in[2];
    const float* embed_w    = (const float*)d_in[3];
    const float* init_w     = (const float*)d_in[4];
    const float* init_b     = (const float*)d_in[5];
    const float* w_ih0      = (const float*)d_in[6];
    const float* w_hh0      = (const float*)d_in[7];
    const float* b_ih0      = (const float*)d_in[8];
    const float* b_hh0      = (const float*)d_in[9];
    const float* w_ih1      = (const float*)d_in[10];
    const float* w_hh1      = (const float*)d_in[11];
    const float* b_ih1      = (const float*)d_in[12];
    const float* b_hh1      = (const float*)d_in[13];
    const float* fc_w       = (const float*)d_in[14];
    const float* fc_b       = (const float*)d_in[15];
    float* out = (float*)d_out;

    const size_t tail = (size_t)BB * TCAP + 2 * BB;     // 13,568
    const size_t predN = (size_t)out_size - tail;       // BB*TT*VV

    // workspace (same layout as validated round 5)
    char* ws = (char*)d_ws;
    int*   order_ws = (int*)(ws + 0);
    int*   len_ws   = (int*)(ws + 1024);
    int*   caps_ws  = (int*)(ws + 2048);
    float* h0a      = (float*)(ws + 2151424);
    float* h0b      = (float*)(ws + 2675712);
    float* h1a      = (float*)(ws + 3200000);
    float* h1b      = (float*)(ws + 3724288);
    float* gi_img   = (float*)(ws + 4248576);
    float* gi_all   = (float*)(ws + 5821440);
    unsigned short* h1x  = (unsigned short*)(ws + 84464640);
    unsigned short* fcwb = (unsigned short*)(ws + 97571840);

    // bf16 staging buffers live in d_out's predictions region (free until gemm_fc
    // rewrites every element at the end; consumed strictly before that).
    char* ob = (char*)d_out;
    unsigned short* imgb  = (unsigned short*)(ob + 0);          //  1,048,576 B
    unsigned short* wihe  = (unsigned short*)(ob + 1048576);    //  1,572,864 B
    unsigned short* wcomb = (unsigned short*)(ob + 4194304);    // 10,485,760 B
    unsigned short* embb  = (unsigned short*)(ob + 16777216);   // 10,240,000 B

    dim3 blk(256);
    hipLaunchKernelGGL(sort_kernel, dim3(1), blk, 0, stream,
                       cap_lens, captions, order_ws, len_ws, caps_ws, out, predN);
    hipLaunchKernelGGL(gather_imgb, dim3(256), blk, 0, stream, image_code, order_ws, imgb);
    hipLaunchKernelGGL(cvt_mat, dim3(1024), blk, 0, stream,
                       init_w, ICC, 0, wcomb, ICC, 1024 * ICC / 8);
    hipLaunchKernelGGL(cvt_mat, dim3(1536), blk, 0, stream,
                       w_ih0, ICC + WDIM, 0, wcomb + (size_t)1024 * ICC, ICC, G3H * ICC / 8);
    hipLaunchKernelGGL(cvt_mat, dim3(384), blk, 0, stream,
                       w_ih0, ICC + WDIM, ICC, wihe, WDIM, G3H * WDIM / 8);
    hipLaunchKernelGGL(cvt_mat, dim3(2500), blk, 0, stream,
                       embed_w, WDIM, 0, embb, WDIM, VV * WDIM / 8);
    hipLaunchKernelGGL(cvt_mat, dim3(2500), blk, 0, stream,
                       fc_w, WDIM, 0, fcwb, WDIM, VV * WDIM / 8);
    hipLaunchKernelGGL(gemm_front, dim3(40, 4), blk, 0, stream,
                       imgb, wcomb, init_b, b_ih0, h0a, h1a, gi_img);
    hipLaunchKernelGGL(gemm_giemb, dim3(24, 200), blk, 0, stream,
                       embb, wihe, gi_img, caps_ws, len_ws, gi_all);

    void* kargs[] = {(void*)&gi_all, (void*)&h0a, (void*)&h0b, (void*)&h1a, (void*)&h1b,
                     (void*)&h1x, (void*)&w_hh0, (void*)&b_hh0, (void*)&w_ih1, (void*)&b_ih1,
                     (void*)&w_hh1, (void*)&b_hh1, (void*)&len_ws};
    hipLaunchCooperativeKernel((void*)gru_persist, dim3(16, 32), dim3(128),
                               kargs, 2 * 8 * HPAD * 4, stream);

    hipLaunchKernelGGL(gemm_fc_mfma, dim3(157, 200), blk, 0, stream,
                       h1x, fcwb, fc_b, len_ws, out);
}

// Round 7
// 2935.914 us; speedup vs baseline: 4.8944x; 4.8944x over previous
//
#include <hip/hip_runtime.h>
#include <hip/hip_bf16.h>

#define BB   256
#define TCAP 51
#define TT   50
#define VV   10000
#define WDIM 512
#define HH   512
#define ICC  2048
#define G3H  1536
#define FCP  8

typedef __attribute__((ext_vector_type(8))) short short8v;
typedef __attribute__((ext_vector_type(4))) float f32x4;

__device__ __forceinline__ unsigned short f2bf(float f) {
    unsigned u; __builtin_memcpy(&u, &f, 4);
    unsigned r = (u + 0x7FFFu + ((u >> 16) & 1u)) >> 16;   // RNE
    return (unsigned short)r;
}
__device__ __forceinline__ float bf2f(unsigned short b) {
    unsigned u = ((unsigned)b) << 16; float f; __builtin_memcpy(&f, &u, 4); return f;
}
__device__ __forceinline__ short8v cvt8(float4 a, float4 b) {
    union { unsigned short u[8]; short8v v; } o;
    o.u[0] = f2bf(a.x); o.u[1] = f2bf(a.y); o.u[2] = f2bf(a.z); o.u[3] = f2bf(a.w);
    o.u[4] = f2bf(b.x); o.u[5] = f2bf(b.y); o.u[6] = f2bf(b.z); o.u[7] = f2bf(b.w);
    return o.v;
}
__device__ __forceinline__ float sigm(float x) { return 1.f / (1.f + expf(-x)); }

// ---------------- sort (stable, descending) + tail outputs (f32) ----------------
__global__ void sort_kernel(const int* __restrict__ cap_lens, const int* __restrict__ captions,
                            int* __restrict__ order_ws, int* __restrict__ len_ws,
                            int* __restrict__ caps_ws, float* __restrict__ out,
                            size_t predN) {
    __shared__ int s_order[BB];
    int i = threadIdx.x;
    int li = cap_lens[i];
    int rank = 0;
    for (int j = 0; j < BB; ++j) {
        int lj = cap_lens[j];
        rank += (lj > li) || (lj == li && j < i);
    }
    s_order[rank] = i;
    __syncthreads();
    int src = s_order[i];
    order_ws[i] = src;
    int len = cap_lens[src] - 1;
    len_ws[i] = len;
    for (int t = 0; t < TCAP; ++t) {
        int c = captions[src * TCAP + t];
        caps_ws[i * TCAP + t] = c;
        out[predN + (size_t)i * TCAP + t] = (float)c;
    }
    out[predN + (size_t)BB * TCAP + i]      = (float)len;
    out[predN + (size_t)BB * TCAP + BB + i] = (float)src;
}

// ---------------- gather image rows (sorted) -> bf16 ----------------
__global__ void gather_imgb(const float* __restrict__ image_code, const int* __restrict__ order_ws,
                            unsigned short* __restrict__ imgb) {
    int i = blockIdx.x * 256 + threadIdx.x;       // 65536 total, 8 elems each
    int p = i >> 8, c8 = (i & 255) << 3;
    const float* s = image_code + (size_t)order_ws[p] * ICC + c8;
    float4 v0 = *(const float4*)s, v1 = *(const float4*)(s + 4);
    *(short8v*)&imgb[(size_t)p * ICC + c8] = cvt8(v0, v1);
}

// ---------------- strided f32 -> bf16 matrix convert (src/dst ld + col offsets) ----------------
__global__ void cvt_mat(const float* __restrict__ src, int src_ld, int src_off,
                        unsigned short* __restrict__ dst, int dst_ld, int dst_off,
                        int cols, int n8) {
    int i = blockIdx.x * 256 + threadIdx.x;
    if (i < n8) {
        int cpr = cols >> 3;
        int row = i / cpr, c8 = (i - row * cpr) << 3;
        const float* s = src + (size_t)row * src_ld + src_off + c8;
        float4 v0 = *(const float4*)s, v1 = *(const float4*)(s + 4);
        *(short8v*)&dst[(size_t)row * dst_ld + dst_off + c8] = cvt8(v0, v1);
    }
}

// ---------------- front GEMM: [256 x 2560] = imgb @ wcomb^T -> h0(bf16), h1(bf16), gi_img ------
__global__ __launch_bounds__(256) void gemm_front(
    const unsigned short* __restrict__ imgb,    // [256][2048]
    const unsigned short* __restrict__ wcomb,   // [2560][2048]
    const float* __restrict__ init_b,           // [1024]
    const float* __restrict__ b_ih0,            // [1536]
    unsigned short* __restrict__ h0b0,          // [256][512] bf16
    unsigned short* __restrict__ hcat0,         // [256][1024] bf16; h1 half = [0..512)
    float* __restrict__ gi_img) {
    const int p0 = blockIdx.y * 64;
    const int c0 = blockIdx.x * 64;
    const int tid = threadIdx.x;
    __shared__ unsigned short As[64][64 + FCP], Bs[64][64 + FCP];
    const int lane = tid & 63, w = tid >> 6;
    f32x4 acc[4] = {};
    for (int k0 = 0; k0 < ICC; k0 += 64) {
#pragma unroll
        for (int v = 0; v < 2; ++v) {
            int e = tid + v * 256;
            int rr = e >> 3, kk = (e & 7) * 8;
            *(short8v*)&As[rr][kk] = *(const short8v*)&imgb[(size_t)(p0 + rr) * ICC + k0 + kk];
            *(short8v*)&Bs[rr][kk] = *(const short8v*)&wcomb[(size_t)(c0 + rr) * ICC + k0 + kk];
        }
        __syncthreads();
#pragma unroll
        for (int ks = 0; ks < 64; ks += 32) {
            short8v a = *(const short8v*)&As[w * 16 + (lane & 15)][ks + (lane >> 4) * 8];
#pragma unroll
            for (int n = 0; n < 4; ++n) {
                short8v b = *(const short8v*)&Bs[n * 16 + (lane & 15)][ks + (lane >> 4) * 8];
                acc[n] = __builtin_amdgcn_mfma_f32_16x16x32_bf16(a, b, acc[n], 0, 0, 0);
            }
        }
        __syncthreads();
    }
#pragma unroll
    for (int n = 0; n < 4; ++n) {
        int cc = c0 + n * 16 + (lane & 15);
#pragma unroll
        for (int r = 0; r < 4; ++r) {
            int pr = p0 + w * 16 + (lane >> 4) * 4 + r;
            float v = acc[n][r];
            if (cc < 1024) {
                v += init_b[cc];
                unsigned short b = f2bf(v);
                if (cc < 512) h0b0[(size_t)pr * 512 + cc] = b;
                else          hcat0[(size_t)pr * 1024 + (cc - 512)] = b;
            } else {
                gi_img[(size_t)pr * G3H + (cc - 1024)] = v + b_ih0[cc - 1024];
            }
        }
    }
}

// ---------------- gi GEMM: gi_all[t,p,:] = emb_bf16 @ w_ihe^T + gi_img ----------------
__global__ __launch_bounds__(256) void gemm_giemb(
    const unsigned short* __restrict__ embb,    // [VV][512]
    const unsigned short* __restrict__ wihe,    // [1536][512]
    const float* __restrict__ gi_img,           // [256][1536]
    const int* __restrict__ caps_ws, const int* __restrict__ len_ws,
    float* __restrict__ gi_all) {
    const int r0 = blockIdx.y * 64;
    const int t = r0 >> 8, p0 = r0 & 255;
    if (len_ws[p0] <= t) return;
    const int c0 = blockIdx.x * 64;
    const int tid = threadIdx.x;
    __shared__ unsigned short As[64][64 + FCP], Bs[64][64 + FCP];
    __shared__ int s_arow[64];
    if (tid < 64) s_arow[tid] = caps_ws[(p0 + tid) * TCAP + t];
    __syncthreads();
    const int lane = tid & 63, w = tid >> 6;
    f32x4 acc[4] = {};
    for (int k0 = 0; k0 < WDIM; k0 += 64) {
#pragma unroll
        for (int v = 0; v < 2; ++v) {
            int e = tid + v * 256;
            int rr = e >> 3, kk = (e & 7) * 8;
            *(short8v*)&As[rr][kk] = *(const short8v*)&embb[(size_t)s_arow[rr] * WDIM + k0 + kk];
            *(short8v*)&Bs[rr][kk] = *(const short8v*)&wihe[(size_t)(c0 + rr) * WDIM + k0 + kk];
        }
        __syncthreads();
#pragma unroll
        for (int ks = 0; ks < 64; ks += 32) {
            short8v a = *(const short8v*)&As[w * 16 + (lane & 15)][ks + (lane >> 4) * 8];
#pragma unroll
            for (int n = 0; n < 4; ++n) {
                short8v b = *(const short8v*)&Bs[n * 16 + (lane & 15)][ks + (lane >> 4) * 8];
                acc[n] = __builtin_amdgcn_mfma_f32_16x16x32_bf16(a, b, acc[n], 0, 0, 0);
            }
        }
        __syncthreads();
    }
#pragma unroll
    for (int n = 0; n < 4; ++n) {
        int cc = c0 + n * 16 + (lane & 15);
#pragma unroll
        for (int r = 0; r < 4; ++r) {
            int pr = p0 + w * 16 + (lane >> 4) * 4 + r;
            if (t < len_ws[pr])
                gi_all[((size_t)t * BB + pr) * G3H + cc] = acc[n][r] + gi_img[(size_t)pr * G3H + cc];
        }
    }
}

// ---------------- GRU layer 0: gates MFMA + in-register gate math ----------------
// grid (8 colgrp, 4 rowgrp), 256 thr. Block owns 64 rows x 64 cols of ALL 3 gates.
__global__ __launch_bounds__(256) void gru_l0(int t,
    const unsigned short* __restrict__ h0c,   // [256][512] bf16 current
    unsigned short* __restrict__ h0n,         // [256][512] bf16 next
    unsigned short* __restrict__ hcx,         // hcat[q] base; x half at [p][512+cc]
    const unsigned short* __restrict__ whh0b, // [1536][512] bf16
    const float* __restrict__ b_hh0,
    const float* __restrict__ gi_all,
    const int* __restrict__ len_ws) {
    const int p0 = blockIdx.y * 64;
    if (len_ws[p0] <= t) return;              // rows never observed again
    const int cc0 = blockIdx.x * 64;
    const int tid = threadIdx.x, lane = tid & 63, w = tid >> 6;
    __shared__ unsigned short As[64][64 + FCP], Bs[64][64 + FCP];
    f32x4 aR[4] = {}, aZ[4] = {}, aN[4] = {};
#pragma unroll
    for (int g = 0; g < 3; ++g) {
        for (int kc = 0; kc < 8; ++kc) {
            int k0 = kc * 64;
#pragma unroll
            for (int v = 0; v < 2; ++v) {
                int e = tid + v * 256;
                int rr = e >> 3, kk = (e & 7) * 8;
                *(short8v*)&As[rr][kk] = *(const short8v*)&h0c[(size_t)(p0 + rr) * 512 + k0 + kk];
                *(short8v*)&Bs[rr][kk] =
                    *(const short8v*)&whh0b[(size_t)(g * 512 + cc0 + rr) * 512 + k0 + kk];
            }
            __syncthreads();
#pragma unroll
            for (int ks = 0; ks < 64; ks += 32) {
                short8v a = *(const short8v*)&As[w * 16 + (lane & 15)][ks + (lane >> 4) * 8];
#pragma unroll
                for (int n = 0; n < 4; ++n) {
                    short8v b = *(const short8v*)&Bs[n * 16 + (lane & 15)][ks + (lane >> 4) * 8];
                    if (g == 0)      aR[n] = __builtin_amdgcn_mfma_f32_16x16x32_bf16(a, b, aR[n], 0, 0, 0);
                    else if (g == 1) aZ[n] = __builtin_amdgcn_mfma_f32_16x16x32_bf16(a, b, aZ[n], 0, 0, 0);
                    else             aN[n] = __builtin_amdgcn_mfma_f32_16x16x32_bf16(a, b, aN[n], 0, 0, 0);
                }
            }
            __syncthreads();
        }
    }
#pragma unroll
    for (int n = 0; n < 4; ++n) {
        int cc = cc0 + n * 16 + (lane & 15);
        float bR = b_hh0[cc], bZ = b_hh0[512 + cc], bN = b_hh0[1024 + cc];
#pragma unroll
        for (int r = 0; r < 4; ++r) {
            int p = p0 + w * 16 + (lane >> 4) * 4 + r;
            const float* gi = gi_all + ((size_t)t * BB + p) * G3H;
            float rr_ = sigm(gi[cc] + aR[n][r] + bR);
            float zz  = sigm(gi[512 + cc] + aZ[n][r] + bZ);
            float nn  = tanhf(gi[1024 + cc] + rr_ * (aN[n][r] + bN));
            float hold = bf2f(h0c[(size_t)p * 512 + cc]);
            float hnew = (t < len_ws[p]) ? (1.f - zz) * nn + zz * hold : hold;
            unsigned short hb = f2bf(hnew);
            h0n[(size_t)p * 512 + cc] = hb;
            hcx[(size_t)p * 1024 + 512 + cc] = hb;
        }
    }
}

// ---------------- GRU layer 1: K=1024 concat [h1|x] GEMM; n-gate split h/x ----------------
__global__ __launch_bounds__(256) void gru_l1(int t,
    const unsigned short* __restrict__ hc,    // hcat[q]: [256][1024] = [h1 | x]
    unsigned short* __restrict__ hnx,         // hcat[q^1] base: write h1 half [p][cc]
    unsigned short* __restrict__ h1x,         // [TT*256][512] bf16 (t-major)
    const unsigned short* __restrict__ wcat1, // [1536][1024] = [w_hh1 | w_ih1]
    const float* __restrict__ b_ih1, const float* __restrict__ b_hh1,
    const int* __restrict__ len_ws) {
    const int p0 = blockIdx.y * 64;
    if (len_ws[p0] <= t) return;
    const int cc0 = blockIdx.x * 64;
    const int tid = threadIdx.x, lane = tid & 63, w = tid >> 6;
    __shared__ unsigned short As[64][64 + FCP], Bs[64][64 + FCP];
    f32x4 aR[4] = {}, aZ[4] = {}, aNH[4] = {}, aNX[4] = {};
#pragma unroll
    for (int g = 0; g < 3; ++g) {
        for (int kc = 0; kc < 16; ++kc) {
            int k0 = kc * 64;
#pragma unroll
            for (int v = 0; v < 2; ++v) {
                int e = tid + v * 256;
                int rr = e >> 3, kk = (e & 7) * 8;
                *(short8v*)&As[rr][kk] = *(const short8v*)&hc[(size_t)(p0 + rr) * 1024 + k0 + kk];
                *(short8v*)&Bs[rr][kk] =
                    *(const short8v*)&wcat1[(size_t)(g * 512 + cc0 + rr) * 1024 + k0 + kk];
            }
            __syncthreads();
#pragma unroll
            for (int ks = 0; ks < 64; ks += 32) {
                short8v a = *(const short8v*)&As[w * 16 + (lane & 15)][ks + (lane >> 4) * 8];
#pragma unroll
                for (int n = 0; n < 4; ++n) {
                    short8v b = *(const short8v*)&Bs[n * 16 + (lane & 15)][ks + (lane >> 4) * 8];
                    if (g == 0)      aR[n] = __builtin_amdgcn_mfma_f32_16x16x32_bf16(a, b, aR[n], 0, 0, 0);
                    else if (g == 1) aZ[n] = __builtin_amdgcn_mfma_f32_16x16x32_bf16(a, b, aZ[n], 0, 0, 0);
                    else if (kc < 8) aNH[n] = __builtin_amdgcn_mfma_f32_16x16x32_bf16(a, b, aNH[n], 0, 0, 0);
                    else             aNX[n] = __builtin_amdgcn_mfma_f32_16x16x32_bf16(a, b, aNX[n], 0, 0, 0);
                }
            }
            __syncthreads();
        }
    }
#pragma unroll
    for (int n = 0; n < 4; ++n) {
        int cc = cc0 + n * 16 + (lane & 15);
        float bR = b_ih1[cc] + b_hh1[cc];
        float bZ = b_ih1[512 + cc] + b_hh1[512 + cc];
        float bNX = b_ih1[1024 + cc], bNH = b_hh1[1024 + cc];
#pragma unroll
        for (int r = 0; r < 4; ++r) {
            int p = p0 + w * 16 + (lane >> 4) * 4 + r;
            float rr_ = sigm(aR[n][r] + bR);
            float zz  = sigm(aZ[n][r] + bZ);
            float nn  = tanhf((aNX[n][r] + bNX) + rr_ * (aNH[n][r] + bNH));
            float hold = bf2f(hc[(size_t)p * 1024 + cc]);     // h1 half
            float hnew = (t < len_ws[p]) ? (1.f - zz) * nn + zz * hold : hold;
            unsigned short hb = f2bf(hnew);
            hnx[(size_t)p * 1024 + cc] = hb;
            h1x[((size_t)t * BB + p) * 512 + cc] = hb;
        }
    }
}

// ---------------- predictions = H1(bf16) @ fc_wb^T + fc_b via MFMA, masked, f32 ----------------
__global__ __launch_bounds__(256) void gemm_fc_mfma(
    const unsigned short* __restrict__ h1x,   // [TT*BB][512] bf16 (t-major rows)
    const unsigned short* __restrict__ fcwb,  // [VV][512]
    const float* __restrict__ fc_b,
    const int* __restrict__ len_ws,
    float* __restrict__ out) {
    const int r0 = blockIdx.y * 64;
    const int t = r0 >> 8, p0 = r0 & 255;
    const int c0 = blockIdx.x * 64;
    const int tid = threadIdx.x;
    if (len_ws[p0] <= t) {
        for (int e = tid; e < 64 * 16; e += 256) {
            int rl = e >> 4, c = c0 + (e & 15) * 4;
            if (c < VV) {
                float4 z = {0.f, 0.f, 0.f, 0.f};
                *(float4*)&out[((size_t)(p0 + rl) * TT + t) * VV + c] = z;
            }
        }
        return;
    }
    __shared__ unsigned short As[64][64 + FCP];
    __shared__ unsigned short Bs[64][64 + FCP];
    const int lane = tid & 63, w = tid >> 6;
    f32x4 acc[4] = {};
    for (int k0 = 0; k0 < HH; k0 += 64) {
#pragma unroll
        for (int v = 0; v < 2; ++v) {
            int e = tid + v * 256;
            int rr = e >> 3, kk = (e & 7) * 8;
            *(short8v*)&As[rr][kk] =
                *(const short8v*)&h1x[((size_t)(t * BB + p0 + rr)) * HH + k0 + kk];
            int bc = c0 + rr;
            short8v bv = {};
            if (bc < VV) bv = *(const short8v*)&fcwb[(size_t)bc * HH + k0 + kk];
            *(short8v*)&Bs[rr][kk] = bv;
        }
        __syncthreads();
#pragma unroll
        for (int ks = 0; ks < 64; ks += 32) {
            short8v a = *(const short8v*)&As[w * 16 + (lane & 15)][ks + (lane >> 4) * 8];
#pragma unroll
            for (int n = 0; n < 4; ++n) {
                short8v b = *(const short8v*)&Bs[n * 16 + (lane & 15)][ks + (lane >> 4) * 8];
                acc[n] = __builtin_amdgcn_mfma_f32_16x16x32_bf16(a, b, acc[n], 0, 0, 0);
            }
        }
        __syncthreads();
    }
#pragma unroll
    for (int n = 0; n < 4; ++n) {
        int c = c0 + n * 16 + (lane & 15);
        if (c < VV) {
            float bias = fc_b[c];
#pragma unroll
            for (int r = 0; r < 4; ++r) {
                int pr = p0 + w * 16 + (lane >> 4) * 4 + r;
                bool act = (t < len_ws[pr]);
                out[((size_t)pr * TT + t) * VV + c] = act ? (acc[n][r] + bias) : 0.f;
            }
        }
    }
}

// ---------------- launch ----------------
extern "C" void kernel_launch(void* const* d_in, const int* in_sizes, int n_in,
                              void* d_out, int out_size, void* d_ws, size_t ws_size,
                              hipStream_t stream) {
    const float* image_code = (const float*)d_in[0];
    const int*   captions   = (const int*)d_in[1];
    const int*   cap_lens   = (const int*)d_in[2];
    const float* embed_w    = (const float*)d_in[3];
    const float* init_w     = (const float*)d_in[4];
    const float* init_b     = (const float*)d_in[5];
    const float* w_ih0      = (const float*)d_in[6];
    const float* w_hh0      = (const float*)d_in[7];
    const float* b_ih0      = (const float*)d_in[8];
    const float* b_hh0      = (const float*)d_in[9];
    const float* w_ih1      = (const float*)d_in[10];
    const float* w_hh1      = (const float*)d_in[11];
    const float* b_ih1      = (const float*)d_in[12];
    const float* b_hh1      = (const float*)d_in[13];
    const float* fc_w       = (const float*)d_in[14];
    const float* fc_b       = (const float*)d_in[15];
    float* out = (float*)d_out;

    const size_t tail = (size_t)BB * TCAP + 2 * BB;     // 13,568
    const size_t predN = (size_t)out_size - tail;       // BB*TT*VV

    // ---- workspace ----
    char* ws = (char*)d_ws;
    int*   order_ws = (int*)(ws + 0);
    int*   len_ws   = (int*)(ws + 1024);
    int*   caps_ws  = (int*)(ws + 2048);
    unsigned short* h0buf0 = (unsigned short*)(ws + 2151424);   // 256x512 bf16
    unsigned short* h0buf1 = (unsigned short*)(ws + 2413568);
    unsigned short* hcat0  = (unsigned short*)(ws + 2675712);   // 256x1024 bf16
    unsigned short* hcat1  = (unsigned short*)(ws + 3200000);
    float* gi_img   = (float*)(ws + 4248576);
    float* gi_all   = (float*)(ws + 5821440);
    unsigned short* h1x  = (unsigned short*)(ws + 84464640);
    unsigned short* fcwb = (unsigned short*)(ws + 97571840);

    // ---- bf16 staging in d_out's predictions region (consumed before fc writes) ----
    char* ob = (char*)d_out;
    unsigned short* imgb   = (unsigned short*)(ob + 0);          //  1,048,576 B
    unsigned short* wihe   = (unsigned short*)(ob + 1048576);    //  1,572,864 B
    unsigned short* wcomb  = (unsigned short*)(ob + 4194304);    // 10,485,760 B
    unsigned short* embb   = (unsigned short*)(ob + 16777216);   // 10,240,000 B
    unsigned short* whh0b  = (unsigned short*)(ob + 27262976);   //  1,572,864 B
    unsigned short* wcat1  = (unsigned short*)(ob + 29360128);   //  3,145,728 B

    dim3 blk(256);
    hipLaunchKernelGGL(sort_kernel, dim3(1), blk, 0, stream,
                       cap_lens, captions, order_ws, len_ws, caps_ws, out, predN);
    hipLaunchKernelGGL(gather_imgb, dim3(256), blk, 0, stream, image_code, order_ws, imgb);
    hipLaunchKernelGGL(cvt_mat, dim3(1024), blk, 0, stream,
                       init_w, ICC, 0, wcomb, ICC, 0, ICC, 1024 * ICC / 8);
    hipLaunchKernelGGL(cvt_mat, dim3(1536), blk, 0, stream,
                       w_ih0, ICC + WDIM, 0, wcomb + (size_t)1024 * ICC, ICC, 0, ICC, G3H * ICC / 8);
    hipLaunchKernelGGL(cvt_mat, dim3(384), blk, 0, stream,
                       w_ih0, ICC + WDIM, ICC, wihe, WDIM, 0, WDIM, G3H * WDIM / 8);
    hipLaunchKernelGGL(cvt_mat, dim3(2500), blk, 0, stream,
                       embed_w, WDIM, 0, embb, WDIM, 0, WDIM, VV * WDIM / 8);
    hipLaunchKernelGGL(cvt_mat, dim3(2500), blk, 0, stream,
                       fc_w, WDIM, 0, fcwb, WDIM, 0, WDIM, VV * WDIM / 8);
    hipLaunchKernelGGL(cvt_mat, dim3(384), blk, 0, stream,
                       w_hh0, WDIM, 0, whh0b, WDIM, 0, WDIM, G3H * WDIM / 8);
    hipLaunchKernelGGL(cvt_mat, dim3(384), blk, 0, stream,
                       w_hh1, WDIM, 0, wcat1, 1024, 0, WDIM, G3H * WDIM / 8);
    hipLaunchKernelGGL(cvt_mat, dim3(384), blk, 0, stream,
                       w_ih1, WDIM, 0, wcat1, 1024, WDIM, WDIM, G3H * WDIM / 8);

    hipLaunchKernelGGL(gemm_front, dim3(40, 4), blk, 0, stream,
                       imgb, wcomb, init_b, b_ih0, h0buf0, hcat0, gi_img);
    hipLaunchKernelGGL(gemm_giemb, dim3(24, 200), blk, 0, stream,
                       embb, wihe, gi_img, caps_ws, len_ws, gi_all);

    unsigned short* h0bufs[2] = {h0buf0, h0buf1};
    unsigned short* hcats[2]  = {hcat0, hcat1};
    for (int t = 0; t < TT; ++t) {
        int q = t & 1;
        hipLaunchKernelGGL(gru_l0, dim3(8, 4), blk, 0, stream,
                           t, h0bufs[q], h0bufs[q ^ 1], hcats[q], whh0b, b_hh0, gi_all, len_ws);
        hipLaunchKernelGGL(gru_l1, dim3(8, 4), blk, 0, stream,
                           t, hcats[q], hcats[q ^ 1], h1x, wcat1, b_ih1, b_hh1, len_ws);
    }

    hipLaunchKernelGGL(gemm_fc_mfma, dim3(157, 200), blk, 0, stream,
                       h1x, fcwb, fc_b, len_ws, out);
}

// Round 8
// 2312.287 us; speedup vs baseline: 6.2145x; 1.2697x over previous
//
#include <hip/hip_runtime.h>
#include <hip/hip_bf16.h>

#define BB   256
#define TCAP 51
#define TT   50
#define VV   10000
#define WDIM 512
#define HH   512
#define ICC  2048
#define G3H  1536
#define FCP  8

typedef __attribute__((ext_vector_type(8))) short short8v;
typedef __attribute__((ext_vector_type(4))) float f32x4;

__device__ __forceinline__ unsigned short f2bf(float f) {
    unsigned u; __builtin_memcpy(&u, &f, 4);
    unsigned r = (u + 0x7FFFu + ((u >> 16) & 1u)) >> 16;   // RNE
    return (unsigned short)r;
}
__device__ __forceinline__ float bf2f(unsigned short b) {
    unsigned u = ((unsigned)b) << 16; float f; __builtin_memcpy(&f, &u, 4); return f;
}
__device__ __forceinline__ short8v cvt8(float4 a, float4 b) {
    union { unsigned short u[8]; short8v v; } o;
    o.u[0] = f2bf(a.x); o.u[1] = f2bf(a.y); o.u[2] = f2bf(a.z); o.u[3] = f2bf(a.w);
    o.u[4] = f2bf(b.x); o.u[5] = f2bf(b.y); o.u[6] = f2bf(b.z); o.u[7] = f2bf(b.w);
    return o.v;
}
__device__ __forceinline__ float sigm(float x) { return 1.f / (1.f + expf(-x)); }

// ---------------- sort (stable, descending) + tail outputs (f32) ----------------
__global__ void sort_kernel(const int* __restrict__ cap_lens, const int* __restrict__ captions,
                            int* __restrict__ order_ws, int* __restrict__ len_ws,
                            int* __restrict__ caps_ws, float* __restrict__ out,
                            size_t predN) {
    __shared__ int s_order[BB];
    int i = threadIdx.x;
    int li = cap_lens[i];
    int rank = 0;
    for (int j = 0; j < BB; ++j) {
        int lj = cap_lens[j];
        rank += (lj > li) || (lj == li && j < i);
    }
    s_order[rank] = i;
    __syncthreads();
    int src = s_order[i];
    order_ws[i] = src;
    int len = cap_lens[src] - 1;
    len_ws[i] = len;
    for (int t = 0; t < TCAP; ++t) {
        int c = captions[src * TCAP + t];
        caps_ws[i * TCAP + t] = c;
        out[predN + (size_t)i * TCAP + t] = (float)c;
    }
    out[predN + (size_t)BB * TCAP + i]      = (float)len;
    out[predN + (size_t)BB * TCAP + BB + i] = (float)src;
}

// ---------------- gather image rows (sorted) -> bf16 ----------------
__global__ void gather_imgb(const float* __restrict__ image_code, const int* __restrict__ order_ws,
                            unsigned short* __restrict__ imgb) {
    int i = blockIdx.x * 256 + threadIdx.x;       // 65536 total, 8 elems each
    int p = i >> 8, c8 = (i & 255) << 3;
    const float* s = image_code + (size_t)order_ws[p] * ICC + c8;
    float4 v0 = *(const float4*)s, v1 = *(const float4*)(s + 4);
    *(short8v*)&imgb[(size_t)p * ICC + c8] = cvt8(v0, v1);
}

// ---------------- strided f32 -> bf16 matrix convert (src/dst ld + col offsets) ----------------
__global__ void cvt_mat(const float* __restrict__ src, int src_ld, int src_off,
                        unsigned short* __restrict__ dst, int dst_ld, int dst_off,
                        int cols, int n8) {
    int i = blockIdx.x * 256 + threadIdx.x;
    if (i < n8) {
        int cpr = cols >> 3;
        int row = i / cpr, c8 = (i - row * cpr) << 3;
        const float* s = src + (size_t)row * src_ld + src_off + c8;
        float4 v0 = *(const float4*)s, v1 = *(const float4*)(s + 4);
        *(short8v*)&dst[(size_t)row * dst_ld + dst_off + c8] = cvt8(v0, v1);
    }
}

// ---------------- front GEMM: [256 x 2560] = imgb @ wcomb^T -> h0(bf16), h1(bf16), gi_img ------
__global__ __launch_bounds__(256) void gemm_front(
    const unsigned short* __restrict__ imgb,    // [256][2048]
    const unsigned short* __restrict__ wcomb,   // [2560][2048]
    const float* __restrict__ init_b,           // [1024]
    const float* __restrict__ b_ih0,            // [1536]
    unsigned short* __restrict__ h0b0,          // [256][512] bf16
    unsigned short* __restrict__ hcat0,         // [256][1024] bf16; h1 half = [0..512)
    float* __restrict__ gi_img) {
    const int p0 = blockIdx.y * 64;
    const int c0 = blockIdx.x * 64;
    const int tid = threadIdx.x;
    __shared__ unsigned short As[64][64 + FCP], Bs[64][64 + FCP];
    const int lane = tid & 63, w = tid >> 6;
    f32x4 acc[4] = {};
    for (int k0 = 0; k0 < ICC; k0 += 64) {
#pragma unroll
        for (int v = 0; v < 2; ++v) {
            int e = tid + v * 256;
            int rr = e >> 3, kk = (e & 7) * 8;
            *(short8v*)&As[rr][kk] = *(const short8v*)&imgb[(size_t)(p0 + rr) * ICC + k0 + kk];
            *(short8v*)&Bs[rr][kk] = *(const short8v*)&wcomb[(size_t)(c0 + rr) * ICC + k0 + kk];
        }
        __syncthreads();
#pragma unroll
        for (int ks = 0; ks < 64; ks += 32) {
            short8v a = *(const short8v*)&As[w * 16 + (lane & 15)][ks + (lane >> 4) * 8];
#pragma unroll
            for (int n = 0; n < 4; ++n) {
                short8v b = *(const short8v*)&Bs[n * 16 + (lane & 15)][ks + (lane >> 4) * 8];
                acc[n] = __builtin_amdgcn_mfma_f32_16x16x32_bf16(a, b, acc[n], 0, 0, 0);
            }
        }
        __syncthreads();
    }
#pragma unroll
    for (int n = 0; n < 4; ++n) {
        int cc = c0 + n * 16 + (lane & 15);
#pragma unroll
        for (int r = 0; r < 4; ++r) {
            int pr = p0 + w * 16 + (lane >> 4) * 4 + r;
            float v = acc[n][r];
            if (cc < 1024) {
                v += init_b[cc];
                unsigned short b = f2bf(v);
                if (cc < 512) h0b0[(size_t)pr * 512 + cc] = b;
                else          hcat0[(size_t)pr * 1024 + (cc - 512)] = b;
            } else {
                gi_img[(size_t)pr * G3H + (cc - 1024)] = v + b_ih0[cc - 1024];
            }
        }
    }
}

// ---------------- gi GEMM: gi_all[t,p,:] = emb_bf16 @ w_ihe^T + gi_img ----------------
__global__ __launch_bounds__(256) void gemm_giemb(
    const unsigned short* __restrict__ embb,    // [VV][512]
    const unsigned short* __restrict__ wihe,    // [1536][512]
    const float* __restrict__ gi_img,           // [256][1536]
    const int* __restrict__ caps_ws, const int* __restrict__ len_ws,
    float* __restrict__ gi_all) {
    const int r0 = blockIdx.y * 64;
    const int t = r0 >> 8, p0 = r0 & 255;
    if (len_ws[p0] <= t) return;
    const int c0 = blockIdx.x * 64;
    const int tid = threadIdx.x;
    __shared__ unsigned short As[64][64 + FCP], Bs[64][64 + FCP];
    __shared__ int s_arow[64];
    if (tid < 64) s_arow[tid] = caps_ws[(p0 + tid) * TCAP + t];
    __syncthreads();
    const int lane = tid & 63, w = tid >> 6;
    f32x4 acc[4] = {};
    for (int k0 = 0; k0 < WDIM; k0 += 64) {
#pragma unroll
        for (int v = 0; v < 2; ++v) {
            int e = tid + v * 256;
            int rr = e >> 3, kk = (e & 7) * 8;
            *(short8v*)&As[rr][kk] = *(const short8v*)&embb[(size_t)s_arow[rr] * WDIM + k0 + kk];
            *(short8v*)&Bs[rr][kk] = *(const short8v*)&wihe[(size_t)(c0 + rr) * WDIM + k0 + kk];
        }
        __syncthreads();
#pragma unroll
        for (int ks = 0; ks < 64; ks += 32) {
            short8v a = *(const short8v*)&As[w * 16 + (lane & 15)][ks + (lane >> 4) * 8];
#pragma unroll
            for (int n = 0; n < 4; ++n) {
                short8v b = *(const short8v*)&Bs[n * 16 + (lane & 15)][ks + (lane >> 4) * 8];
                acc[n] = __builtin_amdgcn_mfma_f32_16x16x32_bf16(a, b, acc[n], 0, 0, 0);
            }
        }
        __syncthreads();
    }
#pragma unroll
    for (int n = 0; n < 4; ++n) {
        int cc = c0 + n * 16 + (lane & 15);
#pragma unroll
        for (int r = 0; r < 4; ++r) {
            int pr = p0 + w * 16 + (lane >> 4) * 4 + r;
            if (t < len_ws[pr])
                gi_all[((size_t)t * BB + pr) * G3H + cc] = acc[n][r] + gi_img[(size_t)pr * G3H + cc];
        }
    }
}

// ---------------- paired GRU stage s: blocks 0-31 do layer0@t=s, blocks 32-63 layer1@t=s-1 ----
__global__ __launch_bounds__(256) void gru_pair(int s,
    unsigned short* __restrict__ h0a, unsigned short* __restrict__ h0b,
    unsigned short* __restrict__ hca, unsigned short* __restrict__ hcb,
    unsigned short* __restrict__ h1x,
    const unsigned short* __restrict__ whh0b,  // [1536][512]
    const float* __restrict__ b_hh0, const float* __restrict__ gi_all,
    const unsigned short* __restrict__ wcat1,  // [1536][1024] = [w_hh1 | w_ih1]
    const float* __restrict__ b_ih1, const float* __restrict__ b_hh1,
    const int* __restrict__ len_ws) {
    const int bid = blockIdx.x;
    const int role = bid >> 5;
    const int sub = bid & 31;
    const int cc0 = (sub & 7) * 64;
    const int p0 = (sub >> 3) * 64;
    const int tid = threadIdx.x, lane = tid & 63, w = tid >> 6;
    __shared__ unsigned short As[64][64 + FCP];
    __shared__ unsigned short Bs[3][64][64 + FCP];

    if (role == 0) {
        // -------- layer 0 at t = s --------
        const int t = s;
        if (t >= TT) return;
        if (len_ws[p0] <= t) return;
        const int q = t & 1;
        const unsigned short* h0c = q ? h0b : h0a;
        unsigned short* h0n = q ? h0a : h0b;
        unsigned short* hcx = q ? hcb : hca;
        f32x4 aR[4] = {}, aZ[4] = {}, aN[4] = {};
        for (int kc = 0; kc < 8; ++kc) {
            int k0 = kc * 64;
#pragma unroll
            for (int v = 0; v < 2; ++v) {
                int e = tid + v * 256;
                int rr = e >> 3, kk = (e & 7) * 8;
                *(short8v*)&As[rr][kk] = *(const short8v*)&h0c[(size_t)(p0 + rr) * 512 + k0 + kk];
#pragma unroll
                for (int g = 0; g < 3; ++g)
                    *(short8v*)&Bs[g][rr][kk] =
                        *(const short8v*)&whh0b[(size_t)(g * 512 + cc0 + rr) * 512 + k0 + kk];
            }
            __syncthreads();
#pragma unroll
            for (int ks = 0; ks < 64; ks += 32) {
                short8v a = *(const short8v*)&As[w * 16 + (lane & 15)][ks + (lane >> 4) * 8];
#pragma unroll
                for (int n = 0; n < 4; ++n) {
                    short8v b0 = *(const short8v*)&Bs[0][n * 16 + (lane & 15)][ks + (lane >> 4) * 8];
                    aR[n] = __builtin_amdgcn_mfma_f32_16x16x32_bf16(a, b0, aR[n], 0, 0, 0);
                    short8v b1 = *(const short8v*)&Bs[1][n * 16 + (lane & 15)][ks + (lane >> 4) * 8];
                    aZ[n] = __builtin_amdgcn_mfma_f32_16x16x32_bf16(a, b1, aZ[n], 0, 0, 0);
                    short8v b2 = *(const short8v*)&Bs[2][n * 16 + (lane & 15)][ks + (lane >> 4) * 8];
                    aN[n] = __builtin_amdgcn_mfma_f32_16x16x32_bf16(a, b2, aN[n], 0, 0, 0);
                }
            }
            __syncthreads();
        }
#pragma unroll
        for (int n = 0; n < 4; ++n) {
            int cc = cc0 + n * 16 + (lane & 15);
            float bR = b_hh0[cc], bZ = b_hh0[512 + cc], bN = b_hh0[1024 + cc];
#pragma unroll
            for (int r = 0; r < 4; ++r) {
                int p = p0 + w * 16 + (lane >> 4) * 4 + r;
                const float* gi = gi_all + ((size_t)t * BB + p) * G3H;
                float rr_ = sigm(gi[cc] + aR[n][r] + bR);
                float zz  = sigm(gi[512 + cc] + aZ[n][r] + bZ);
                float nn  = tanhf(gi[1024 + cc] + rr_ * (aN[n][r] + bN));
                float hold = bf2f(h0c[(size_t)p * 512 + cc]);
                float hnew = (t < len_ws[p]) ? (1.f - zz) * nn + zz * hold : hold;
                unsigned short hb = f2bf(hnew);
                h0n[(size_t)p * 512 + cc] = hb;
                hcx[(size_t)p * 1024 + 512 + cc] = hb;
            }
        }
        return;
    }
    // -------- layer 1 at t = s-1 --------
    const int t = s - 1;
    if (t < 0) return;
    if (len_ws[p0] <= t) return;
    const int q = t & 1;
    const unsigned short* hc = q ? hcb : hca;
    unsigned short* hnx = q ? hca : hcb;
    f32x4 aR[4] = {}, aZ[4] = {}, aNH[4] = {}, aNX[4] = {};
    for (int kc = 0; kc < 16; ++kc) {
        int k0 = kc * 64;
#pragma unroll
        for (int v = 0; v < 2; ++v) {
            int e = tid + v * 256;
            int rr = e >> 3, kk = (e & 7) * 8;
            *(short8v*)&As[rr][kk] = *(const short8v*)&hc[(size_t)(p0 + rr) * 1024 + k0 + kk];
#pragma unroll
            for (int g = 0; g < 3; ++g)
                *(short8v*)&Bs[g][rr][kk] =
                    *(const short8v*)&wcat1[(size_t)(g * 512 + cc0 + rr) * 1024 + k0 + kk];
        }
        __syncthreads();
#pragma unroll
        for (int ks = 0; ks < 64; ks += 32) {
            short8v a = *(const short8v*)&As[w * 16 + (lane & 15)][ks + (lane >> 4) * 8];
#pragma unroll
            for (int n = 0; n < 4; ++n) {
                short8v b0 = *(const short8v*)&Bs[0][n * 16 + (lane & 15)][ks + (lane >> 4) * 8];
                aR[n] = __builtin_amdgcn_mfma_f32_16x16x32_bf16(a, b0, aR[n], 0, 0, 0);
                short8v b1 = *(const short8v*)&Bs[1][n * 16 + (lane & 15)][ks + (lane >> 4) * 8];
                aZ[n] = __builtin_amdgcn_mfma_f32_16x16x32_bf16(a, b1, aZ[n], 0, 0, 0);
                short8v b2 = *(const short8v*)&Bs[2][n * 16 + (lane & 15)][ks + (lane >> 4) * 8];
                if (kc < 8) aNH[n] = __builtin_amdgcn_mfma_f32_16x16x32_bf16(a, b2, aNH[n], 0, 0, 0);
                else        aNX[n] = __builtin_amdgcn_mfma_f32_16x16x32_bf16(a, b2, aNX[n], 0, 0, 0);
            }
        }
        __syncthreads();
    }
#pragma unroll
    for (int n = 0; n < 4; ++n) {
        int cc = cc0 + n * 16 + (lane & 15);
        float bR = b_ih1[cc] + b_hh1[cc];
        float bZ = b_ih1[512 + cc] + b_hh1[512 + cc];
        float bNX = b_ih1[1024 + cc], bNH = b_hh1[1024 + cc];
#pragma unroll
        for (int r = 0; r < 4; ++r) {
            int p = p0 + w * 16 + (lane >> 4) * 4 + r;
            float rr_ = sigm(aR[n][r] + bR);
            float zz  = sigm(aZ[n][r] + bZ);
            float nn  = tanhf((aNX[n][r] + bNX) + rr_ * (aNH[n][r] + bNH));
            float hold = bf2f(hc[(size_t)p * 1024 + cc]);     // h1 half
            float hnew = (t < len_ws[p]) ? (1.f - zz) * nn + zz * hold : hold;
            unsigned short hb = f2bf(hnew);
            hnx[(size_t)p * 1024 + cc] = hb;
            h1x[((size_t)t * BB + p) * 512 + cc] = hb;
        }
    }
}

// ---------------- predictions = H1(bf16) @ fc_wb^T + fc_b via MFMA, masked, f32 ----------------
__global__ __launch_bounds__(256) void gemm_fc_mfma(
    const unsigned short* __restrict__ h1x,   // [TT*BB][512] bf16 (t-major rows)
    const unsigned short* __restrict__ fcwb,  // [VV][512]
    const float* __restrict__ fc_b,
    const int* __restrict__ len_ws,
    float* __restrict__ out) {
    const int r0 = blockIdx.y * 64;
    const int t = r0 >> 8, p0 = r0 & 255;
    const int c0 = blockIdx.x * 64;
    const int tid = threadIdx.x;
    if (len_ws[p0] <= t) {
        for (int e = tid; e < 64 * 16; e += 256) {
            int rl = e >> 4, c = c0 + (e & 15) * 4;
            if (c < VV) {
                float4 z = {0.f, 0.f, 0.f, 0.f};
                *(float4*)&out[((size_t)(p0 + rl) * TT + t) * VV + c] = z;
            }
        }
        return;
    }
    __shared__ unsigned short As[64][64 + FCP];
    __shared__ unsigned short Bs[64][64 + FCP];
    const int lane = tid & 63, w = tid >> 6;
    f32x4 acc[4] = {};
    for (int k0 = 0; k0 < HH; k0 += 64) {
#pragma unroll
        for (int v = 0; v < 2; ++v) {
            int e = tid + v * 256;
            int rr = e >> 3, kk = (e & 7) * 8;
            *(short8v*)&As[rr][kk] =
                *(const short8v*)&h1x[((size_t)(t * BB + p0 + rr)) * HH + k0 + kk];
            int bc = c0 + rr;
            short8v bv = {};
            if (bc < VV) bv = *(const short8v*)&fcwb[(size_t)bc * HH + k0 + kk];
            *(short8v*)&Bs[rr][kk] = bv;
        }
        __syncthreads();
#pragma unroll
        for (int ks = 0; ks < 64; ks += 32) {
            short8v a = *(const short8v*)&As[w * 16 + (lane & 15)][ks + (lane >> 4) * 8];
#pragma unroll
            for (int n = 0; n < 4; ++n) {
                short8v b = *(const short8v*)&Bs[n * 16 + (lane & 15)][ks + (lane >> 4) * 8];
                acc[n] = __builtin_amdgcn_mfma_f32_16x16x32_bf16(a, b, acc[n], 0, 0, 0);
            }
        }
        __syncthreads();
    }
#pragma unroll
    for (int n = 0; n < 4; ++n) {
        int c = c0 + n * 16 + (lane & 15);
        if (c < VV) {
            float bias = fc_b[c];
#pragma unroll
            for (int r = 0; r < 4; ++r) {
                int pr = p0 + w * 16 + (lane >> 4) * 4 + r;
                bool act = (t < len_ws[pr]);
                out[((size_t)pr * TT + t) * VV + c] = act ? (acc[n][r] + bias) : 0.f;
            }
        }
    }
}

// ---------------- launch ----------------
extern "C" void kernel_launch(void* const* d_in, const int* in_sizes, int n_in,
                              void* d_out, int out_size, void* d_ws, size_t ws_size,
                              hipStream_t stream) {
    const float* image_code = (const float*)d_in[0];
    const int*   captions   = (const int*)d_in[1];
    const int*   cap_lens   = (const int*)d_in[2];
    const float* embed_w    = (const float*)d_in[3];
    const float* init_w     = (const float*)d_in[4];
    const float* init_b     = (const float*)d_in[5];
    const float* w_ih0      = (const float*)d_in[6];
    const float* w_hh0      = (const float*)d_in[7];
    const float* b_ih0      = (const float*)d_in[8];
    const float* b_hh0      = (const float*)d_in[9];
    const float* w_ih1      = (const float*)d_in[10];
    const float* w_hh1      = (const float*)d_in[11];
    const float* b_ih1      = (const float*)d_in[12];
    const float* b_hh1      = (const float*)d_in[13];
    const float* fc_w       = (const float*)d_in[14];
    const float* fc_b       = (const float*)d_in[15];
    float* out = (float*)d_out;

    const size_t tail = (size_t)BB * TCAP + 2 * BB;     // 13,568
    const size_t predN = (size_t)out_size - tail;       // BB*TT*VV

    // ---- workspace ----
    char* ws = (char*)d_ws;
    int*   order_ws = (int*)(ws + 0);
    int*   len_ws   = (int*)(ws + 1024);
    int*   caps_ws  = (int*)(ws + 2048);
    unsigned short* h0buf0 = (unsigned short*)(ws + 2151424);   // 256x512 bf16
    unsigned short* h0buf1 = (unsigned short*)(ws + 2413568);
    unsigned short* hcat0  = (unsigned short*)(ws + 2675712);   // 256x1024 bf16
    unsigned short* hcat1  = (unsigned short*)(ws + 3200000);
    float* gi_img   = (float*)(ws + 4248576);
    float* gi_all   = (float*)(ws + 5821440);
    unsigned short* h1x  = (unsigned short*)(ws + 84464640);
    unsigned short* fcwb = (unsigned short*)(ws + 97571840);

    // ---- bf16 staging in d_out's predictions region (consumed before fc writes) ----
    char* ob = (char*)d_out;
    unsigned short* imgb   = (unsigned short*)(ob + 0);          //  1,048,576 B
    unsigned short* wihe   = (unsigned short*)(ob + 1048576);    //  1,572,864 B
    unsigned short* wcomb  = (unsigned short*)(ob + 4194304);    // 10,485,760 B
    unsigned short* embb   = (unsigned short*)(ob + 16777216);   // 10,240,000 B
    unsigned short* whh0b  = (unsigned short*)(ob + 27262976);   //  1,572,864 B
    unsigned short* wcat1  = (unsigned short*)(ob + 29360128);   //  3,145,728 B

    dim3 blk(256);
    hipLaunchKernelGGL(sort_kernel, dim3(1), blk, 0, stream,
                       cap_lens, captions, order_ws, len_ws, caps_ws, out, predN);
    hipLaunchKernelGGL(gather_imgb, dim3(256), blk, 0, stream, image_code, order_ws, imgb);
    hipLaunchKernelGGL(cvt_mat, dim3(1024), blk, 0, stream,
                       init_w, ICC, 0, wcomb, ICC, 0, ICC, 1024 * ICC / 8);
    hipLaunchKernelGGL(cvt_mat, dim3(1536), blk, 0, stream,
                       w_ih0, ICC + WDIM, 0, wcomb + (size_t)1024 * ICC, ICC, 0, ICC, G3H * ICC / 8);
    hipLaunchKernelGGL(cvt_mat, dim3(384), blk, 0, stream,
                       w_ih0, ICC + WDIM, ICC, wihe, WDIM, 0, WDIM, G3H * WDIM / 8);
    hipLaunchKernelGGL(cvt_mat, dim3(2500), blk, 0, stream,
                       embed_w, WDIM, 0, embb, WDIM, 0, WDIM, VV * WDIM / 8);
    hipLaunchKernelGGL(cvt_mat, dim3(2500), blk, 0, stream,
                       fc_w, WDIM, 0, fcwb, WDIM, 0, WDIM, VV * WDIM / 8);
    hipLaunchKernelGGL(cvt_mat, dim3(384), blk, 0, stream,
                       w_hh0, WDIM, 0, whh0b, WDIM, 0, WDIM, G3H * WDIM / 8);
    hipLaunchKernelGGL(cvt_mat, dim3(384), blk, 0, stream,
                       w_hh1, WDIM, 0, wcat1, 1024, 0, WDIM, G3H * WDIM / 8);
    hipLaunchKernelGGL(cvt_mat, dim3(384), blk, 0, stream,
                       w_ih1, WDIM, 0, wcat1, 1024, WDIM, WDIM, G3H * WDIM / 8);

    hipLaunchKernelGGL(gemm_front, dim3(40, 4), blk, 0, stream,
                       imgb, wcomb, init_b, b_ih0, h0buf0, hcat0, gi_img);
    hipLaunchKernelGGL(gemm_giemb, dim3(24, 200), blk, 0, stream,
                       embb, wihe, gi_img, caps_ws, len_ws, gi_all);

    // 51 paired stages: stage s runs layer0@t=s (s<TT) and layer1@t=s-1 (s>=1)
    for (int s = 0; s <= TT; ++s) {
        hipLaunchKernelGGL(gru_pair, dim3(64), blk, 0, stream,
                           s, h0buf0, h0buf1, hcat0, hcat1, h1x,
                           whh0b, b_hh0, gi_all, wcat1, b_ih1, b_hh1, len_ws);
    }

    hipLaunchKernelGGL(gemm_fc_mfma, dim3(157, 200), blk, 0, stream,
                       h1x, fcwb, fc_b, len_ws, out);
}

// Round 9
// 1351.902 us; speedup vs baseline: 10.6292x; 1.7104x over previous
//
#include <hip/hip_runtime.h>
#include <hip/hip_bf16.h>

#define BB   256
#define TCAP 51
#define TT   50
#define VV   10000
#define WDIM 512
#define HH   512
#define ICC  2048
#define G3H  1536
#define FCP  8

typedef __attribute__((ext_vector_type(8))) short short8v;
typedef __attribute__((ext_vector_type(4))) float f32x4;

__device__ __forceinline__ unsigned short f2bf(float f) {
    unsigned u; __builtin_memcpy(&u, &f, 4);
    unsigned r = (u + 0x7FFFu + ((u >> 16) & 1u)) >> 16;   // RNE
    return (unsigned short)r;
}
__device__ __forceinline__ float bf2f(unsigned short b) {
    unsigned u = ((unsigned)b) << 16; float f; __builtin_memcpy(&f, &u, 4); return f;
}
__device__ __forceinline__ short8v cvt8(float4 a, float4 b) {
    union { unsigned short u[8]; short8v v; } o;
    o.u[0] = f2bf(a.x); o.u[1] = f2bf(a.y); o.u[2] = f2bf(a.z); o.u[3] = f2bf(a.w);
    o.u[4] = f2bf(b.x); o.u[5] = f2bf(b.y); o.u[6] = f2bf(b.z); o.u[7] = f2bf(b.w);
    return o.v;
}
__device__ __forceinline__ float sigm(float x) { return 1.f / (1.f + expf(-x)); }

// ---------------- sort (stable, descending) + tail outputs (f32) ----------------
__global__ void sort_kernel(const int* __restrict__ cap_lens, const int* __restrict__ captions,
                            int* __restrict__ order_ws, int* __restrict__ len_ws,
                            int* __restrict__ caps_ws, float* __restrict__ out,
                            size_t predN) {
    __shared__ int s_order[BB];
    int i = threadIdx.x;
    int li = cap_lens[i];
    int rank = 0;
    for (int j = 0; j < BB; ++j) {
        int lj = cap_lens[j];
        rank += (lj > li) || (lj == li && j < i);
    }
    s_order[rank] = i;
    __syncthreads();
    int src = s_order[i];
    order_ws[i] = src;
    int len = cap_lens[src] - 1;
    len_ws[i] = len;
    for (int t = 0; t < TCAP; ++t) {
        int c = captions[src * TCAP + t];
        caps_ws[i * TCAP + t] = c;
        out[predN + (size_t)i * TCAP + t] = (float)c;
    }
    out[predN + (size_t)BB * TCAP + i]      = (float)len;
    out[predN + (size_t)BB * TCAP + BB + i] = (float)src;
}

// ---------------- gather image rows (sorted) -> bf16 ----------------
__global__ void gather_imgb(const float* __restrict__ image_code, const int* __restrict__ order_ws,
                            unsigned short* __restrict__ imgb) {
    int i = blockIdx.x * 256 + threadIdx.x;       // 65536 total, 8 elems each
    int p = i >> 8, c8 = (i & 255) << 3;
    const float* s = image_code + (size_t)order_ws[p] * ICC + c8;
    float4 v0 = *(const float4*)s, v1 = *(const float4*)(s + 4);
    *(short8v*)&imgb[(size_t)p * ICC + c8] = cvt8(v0, v1);
}

// ---------------- strided f32 -> bf16 matrix convert ----------------
__global__ void cvt_mat(const float* __restrict__ src, int src_ld, int src_off,
                        unsigned short* __restrict__ dst, int dst_ld, int dst_off,
                        int cols, int n8) {
    int i = blockIdx.x * 256 + threadIdx.x;
    if (i < n8) {
        int cpr = cols >> 3;
        int row = i / cpr, c8 = (i - row * cpr) << 3;
        const float* s = src + (size_t)row * src_ld + src_off + c8;
        float4 v0 = *(const float4*)s, v1 = *(const float4*)(s + 4);
        *(short8v*)&dst[(size_t)row * dst_ld + dst_off + c8] = cvt8(v0, v1);
    }
}

// ---------------- front GEMM: [256 x 2560] = imgb @ wcomb^T -> h0, h1 (bf16), gi_img ------
__global__ __launch_bounds__(256) void gemm_front(
    const unsigned short* __restrict__ imgb,    // [256][2048]
    const unsigned short* __restrict__ wcomb,   // [2560][2048]
    const float* __restrict__ init_b,           // [1024]
    const float* __restrict__ b_ih0,            // [1536]
    unsigned short* __restrict__ h0s0,          // [256][512] bf16
    unsigned short* __restrict__ h1s0,          // [256][512] bf16
    float* __restrict__ gi_img) {
    const int p0 = blockIdx.y * 64;
    const int c0 = blockIdx.x * 64;
    const int tid = threadIdx.x;
    __shared__ unsigned short As[64][64 + FCP], Bs[64][64 + FCP];
    const int lane = tid & 63, w = tid >> 6;
    f32x4 acc[4] = {};
    for (int k0 = 0; k0 < ICC; k0 += 64) {
#pragma unroll
        for (int v = 0; v < 2; ++v) {
            int e = tid + v * 256;
            int rr = e >> 3, kk = (e & 7) * 8;
            *(short8v*)&As[rr][kk] = *(const short8v*)&imgb[(size_t)(p0 + rr) * ICC + k0 + kk];
            *(short8v*)&Bs[rr][kk] = *(const short8v*)&wcomb[(size_t)(c0 + rr) * ICC + k0 + kk];
        }
        __syncthreads();
#pragma unroll
        for (int ks = 0; ks < 64; ks += 32) {
            short8v a = *(const short8v*)&As[w * 16 + (lane & 15)][ks + (lane >> 4) * 8];
#pragma unroll
            for (int n = 0; n < 4; ++n) {
                short8v b = *(const short8v*)&Bs[n * 16 + (lane & 15)][ks + (lane >> 4) * 8];
                acc[n] = __builtin_amdgcn_mfma_f32_16x16x32_bf16(a, b, acc[n], 0, 0, 0);
            }
        }
        __syncthreads();
    }
#pragma unroll
    for (int n = 0; n < 4; ++n) {
        int cc = c0 + n * 16 + (lane & 15);
#pragma unroll
        for (int r = 0; r < 4; ++r) {
            int pr = p0 + w * 16 + (lane >> 4) * 4 + r;
            float v = acc[n][r];
            if (cc < 1024) {
                v += init_b[cc];
                unsigned short b = f2bf(v);
                if (cc < 512) h0s0[(size_t)pr * 512 + cc] = b;
                else          h1s0[(size_t)pr * 512 + (cc - 512)] = b;
            } else {
                gi_img[(size_t)pr * G3H + (cc - 1024)] = v + b_ih0[cc - 1024];
            }
        }
    }
}

// ---------------- gi GEMM: gi_all[t,p,:] = emb_bf16 @ w_ihe^T + gi_img ----------------
__global__ __launch_bounds__(256) void gemm_giemb(
    const unsigned short* __restrict__ embb,    // [VV][512]
    const unsigned short* __restrict__ wihe,    // [1536][512]
    const float* __restrict__ gi_img,           // [256][1536]
    const int* __restrict__ caps_ws, const int* __restrict__ len_ws,
    float* __restrict__ gi_all) {
    const int r0 = blockIdx.y * 64;
    const int t = r0 >> 8, p0 = r0 & 255;
    if (len_ws[p0] <= t) return;
    const int c0 = blockIdx.x * 64;
    const int tid = threadIdx.x;
    __shared__ unsigned short As[64][64 + FCP], Bs[64][64 + FCP];
    __shared__ int s_arow[64];
    if (tid < 64) s_arow[tid] = caps_ws[(p0 + tid) * TCAP + t];
    __syncthreads();
    const int lane = tid & 63, w = tid >> 6;
    f32x4 acc[4] = {};
    for (int k0 = 0; k0 < WDIM; k0 += 64) {
#pragma unroll
        for (int v = 0; v < 2; ++v) {
            int e = tid + v * 256;
            int rr = e >> 3, kk = (e & 7) * 8;
            *(short8v*)&As[rr][kk] = *(const short8v*)&embb[(size_t)s_arow[rr] * WDIM + k0 + kk];
            *(short8v*)&Bs[rr][kk] = *(const short8v*)&wihe[(size_t)(c0 + rr) * WDIM + k0 + kk];
        }
        __syncthreads();
#pragma unroll
        for (int ks = 0; ks < 64; ks += 32) {
            short8v a = *(const short8v*)&As[w * 16 + (lane & 15)][ks + (lane >> 4) * 8];
#pragma unroll
            for (int n = 0; n < 4; ++n) {
                short8v b = *(const short8v*)&Bs[n * 16 + (lane & 15)][ks + (lane >> 4) * 8];
                acc[n] = __builtin_amdgcn_mfma_f32_16x16x32_bf16(a, b, acc[n], 0, 0, 0);
            }
        }
        __syncthreads();
    }
#pragma unroll
    for (int n = 0; n < 4; ++n) {
        int cc = c0 + n * 16 + (lane & 15);
#pragma unroll
        for (int r = 0; r < 4; ++r) {
            int pr = p0 + w * 16 + (lane >> 4) * 4 + r;
            if (t < len_ws[pr])
                gi_all[((size_t)t * BB + pr) * G3H + cc] = acc[n][r] + gi_img[(size_t)pr * G3H + cc];
        }
    }
}

// ---------------- 3-role pipelined GRU stage ----------------
// stage s, 96 blocks: role0 (blk 0-31)  = layer0 @ t=s      (w_hh0*h0 + gates -> h0')
//                     role1 (blk 32-63) = gx1    @ t=s-1    (w_ih1*h0(t) + b_ih1 -> gx f32)
//                     role2 (blk 64-95) = layer1h @ t=s-2   (w_hh1*h1 + gx -> gates -> h1', h1x)
// All roles: K=512, 8 staged iterations, register-prefetch overlaps loads with MFMA.
__global__ __launch_bounds__(256) void gru_stage(int s,
    const unsigned short* __restrict__ h0_rd, unsigned short* __restrict__ h0_wr,
    float* __restrict__ gx_wr, const float* __restrict__ gx_rd,
    const unsigned short* __restrict__ h1_rd, unsigned short* __restrict__ h1_wr,
    unsigned short* __restrict__ h1x,
    const unsigned short* __restrict__ whh0b,   // [1536][512]
    const unsigned short* __restrict__ wih1b,   // [1536][512]
    const unsigned short* __restrict__ whh1b,   // [1536][512]
    const float* __restrict__ b_hh0, const float* __restrict__ gi_all,
    const float* __restrict__ b_ih1, const float* __restrict__ b_hh1,
    const int* __restrict__ len_ws) {
    const int role = blockIdx.x >> 5;
    const int sub = blockIdx.x & 31;
    const int cc0 = (sub & 7) * 64;
    const int p0 = (sub >> 3) * 64;
    const int t = s - role;
    if (t < 0 || t >= TT) return;
    if (len_ws[p0] <= t) return;
    const int tid = threadIdx.x, lane = tid & 63, w = tid >> 6;
    __shared__ unsigned short As[64][72];
    __shared__ unsigned short Bs[3][64][72];
    const unsigned short* Arows = (role == 2) ? h1_rd : h0_rd;   // role0/1 read h0, role2 h1
    const unsigned short* Bw = (role == 0) ? whh0b : (role == 1) ? wih1b : whh1b;
    const int rr0 = tid >> 3, kk0 = (tid & 7) * 8;
    f32x4 aG0[4] = {}, aG1[4] = {}, aG2[4] = {};
    short8v pa0, pa1, pb00, pb01, pb02, pb10, pb11, pb12;

#define LOADK(KC) {                                                                  \
    size_t ko = (size_t)(KC) * 64 + kk0;                                             \
    pa0  = *(const short8v*)&Arows[(size_t)(p0 + rr0) * 512 + ko];                   \
    pa1  = *(const short8v*)&Arows[(size_t)(p0 + rr0 + 32) * 512 + ko];              \
    pb00 = *(const short8v*)&Bw[(size_t)(cc0 + rr0) * 512 + ko];                     \
    pb01 = *(const short8v*)&Bw[(size_t)(512 + cc0 + rr0) * 512 + ko];               \
    pb02 = *(const short8v*)&Bw[(size_t)(1024 + cc0 + rr0) * 512 + ko];              \
    pb10 = *(const short8v*)&Bw[(size_t)(cc0 + rr0 + 32) * 512 + ko];                \
    pb11 = *(const short8v*)&Bw[(size_t)(512 + cc0 + rr0 + 32) * 512 + ko];          \
    pb12 = *(const short8v*)&Bw[(size_t)(1024 + cc0 + rr0 + 32) * 512 + ko]; }

    LOADK(0);
    for (int kc = 0; kc < 8; ++kc) {
        if (kc) __syncthreads();                   // WAR: prev MFMA reads done
        *(short8v*)&As[rr0][kk0] = pa0;
        *(short8v*)&As[rr0 + 32][kk0] = pa1;
        *(short8v*)&Bs[0][rr0][kk0] = pb00;
        *(short8v*)&Bs[1][rr0][kk0] = pb01;
        *(short8v*)&Bs[2][rr0][kk0] = pb02;
        *(short8v*)&Bs[0][rr0 + 32][kk0] = pb10;
        *(short8v*)&Bs[1][rr0 + 32][kk0] = pb11;
        *(short8v*)&Bs[2][rr0 + 32][kk0] = pb12;
        __syncthreads();                           // RAW: tiles visible
        if (kc < 7) LOADK(kc + 1);                 // prefetch overlaps MFMA below
#pragma unroll
        for (int ks = 0; ks < 64; ks += 32) {
            short8v a = *(const short8v*)&As[w * 16 + (lane & 15)][ks + (lane >> 4) * 8];
#pragma unroll
            for (int n = 0; n < 4; ++n) {
                int br = n * 16 + (lane & 15), bk = ks + (lane >> 4) * 8;
                short8v b0 = *(const short8v*)&Bs[0][br][bk];
                aG0[n] = __builtin_amdgcn_mfma_f32_16x16x32_bf16(a, b0, aG0[n], 0, 0, 0);
                short8v b1 = *(const short8v*)&Bs[1][br][bk];
                aG1[n] = __builtin_amdgcn_mfma_f32_16x16x32_bf16(a, b1, aG1[n], 0, 0, 0);
                short8v b2 = *(const short8v*)&Bs[2][br][bk];
                aG2[n] = __builtin_amdgcn_mfma_f32_16x16x32_bf16(a, b2, aG2[n], 0, 0, 0);
            }
        }
    }
#undef LOADK

    if (role == 0) {
        // layer 0 gate math: gi_all precomputed x-gates
#pragma unroll
        for (int n = 0; n < 4; ++n) {
            int cc = cc0 + n * 16 + (lane & 15);
            float bR = b_hh0[cc], bZ = b_hh0[512 + cc], bN = b_hh0[1024 + cc];
#pragma unroll
            for (int r = 0; r < 4; ++r) {
                int p = p0 + w * 16 + (lane >> 4) * 4 + r;
                const float* gi = gi_all + ((size_t)t * BB + p) * G3H;
                float rr_ = sigm(gi[cc] + aG0[n][r] + bR);
                float zz  = sigm(gi[512 + cc] + aG1[n][r] + bZ);
                float nn  = tanhf(gi[1024 + cc] + rr_ * (aG2[n][r] + bN));
                float hold = bf2f(h0_rd[(size_t)p * 512 + cc]);
                float hnew = (t < len_ws[p]) ? (1.f - zz) * nn + zz * hold : hold;
                h0_wr[(size_t)p * 512 + cc] = f2bf(hnew);
            }
        }
    } else if (role == 1) {
        // gx1: x-gates of layer1 = w_ih1 @ h0(t) + b_ih1, f32
#pragma unroll
        for (int n = 0; n < 4; ++n) {
            int cc = cc0 + n * 16 + (lane & 15);
            float bR = b_ih1[cc], bZ = b_ih1[512 + cc], bN = b_ih1[1024 + cc];
#pragma unroll
            for (int r = 0; r < 4; ++r) {
                int p = p0 + w * 16 + (lane >> 4) * 4 + r;
                float* gx = gx_wr + (size_t)p * G3H;
                gx[cc]        = aG0[n][r] + bR;
                gx[512 + cc]  = aG1[n][r] + bZ;
                gx[1024 + cc] = aG2[n][r] + bN;
            }
        }
    } else {
        // layer1h: gates = gx + w_hh1 @ h1
#pragma unroll
        for (int n = 0; n < 4; ++n) {
            int cc = cc0 + n * 16 + (lane & 15);
            float bR = b_hh1[cc], bZ = b_hh1[512 + cc], bN = b_hh1[1024 + cc];
#pragma unroll
            for (int r = 0; r < 4; ++r) {
                int p = p0 + w * 16 + (lane >> 4) * 4 + r;
                const float* gx = gx_rd + (size_t)p * G3H;
                float rr_ = sigm(gx[cc] + aG0[n][r] + bR);
                float zz  = sigm(gx[512 + cc] + aG1[n][r] + bZ);
                float nn  = tanhf(gx[1024 + cc] + rr_ * (aG2[n][r] + bN));
                float hold = bf2f(h1_rd[(size_t)p * 512 + cc]);
                float hnew = (t < len_ws[p]) ? (1.f - zz) * nn + zz * hold : hold;
                unsigned short hb = f2bf(hnew);
                h1_wr[(size_t)p * 512 + cc] = hb;
                h1x[((size_t)t * BB + p) * 512 + cc] = hb;
            }
        }
    }
}

// ---------------- predictions = H1(bf16) @ fc_wb^T + fc_b via MFMA, masked, f32 ----------------
__global__ __launch_bounds__(256) void gemm_fc_mfma(
    const unsigned short* __restrict__ h1x,   // [TT*BB][512] bf16 (t-major rows)
    const unsigned short* __restrict__ fcwb,  // [VV][512]
    const float* __restrict__ fc_b,
    const int* __restrict__ len_ws,
    float* __restrict__ out) {
    const int r0 = blockIdx.y * 64;
    const int t = r0 >> 8, p0 = r0 & 255;
    const int c0 = blockIdx.x * 64;
    const int tid = threadIdx.x;
    if (len_ws[p0] <= t) {
        for (int e = tid; e < 64 * 16; e += 256) {
            int rl = e >> 4, c = c0 + (e & 15) * 4;
            if (c < VV) {
                float4 z = {0.f, 0.f, 0.f, 0.f};
                *(float4*)&out[((size_t)(p0 + rl) * TT + t) * VV + c] = z;
            }
        }
        return;
    }
    __shared__ unsigned short As[64][64 + FCP];
    __shared__ unsigned short Bs[64][64 + FCP];
    const int lane = tid & 63, w = tid >> 6;
    f32x4 acc[4] = {};
    for (int k0 = 0; k0 < HH; k0 += 64) {
#pragma unroll
        for (int v = 0; v < 2; ++v) {
            int e = tid + v * 256;
            int rr = e >> 3, kk = (e & 7) * 8;
            *(short8v*)&As[rr][kk] =
                *(const short8v*)&h1x[((size_t)(t * BB + p0 + rr)) * HH + k0 + kk];
            int bc = c0 + rr;
            short8v bv = {};
            if (bc < VV) bv = *(const short8v*)&fcwb[(size_t)bc * HH + k0 + kk];
            *(short8v*)&Bs[rr][kk] = bv;
        }
        __syncthreads();
#pragma unroll
        for (int ks = 0; ks < 64; ks += 32) {
            short8v a = *(const short8v*)&As[w * 16 + (lane & 15)][ks + (lane >> 4) * 8];
#pragma unroll
            for (int n = 0; n < 4; ++n) {
                short8v b = *(const short8v*)&Bs[n * 16 + (lane & 15)][ks + (lane >> 4) * 8];
                acc[n] = __builtin_amdgcn_mfma_f32_16x16x32_bf16(a, b, acc[n], 0, 0, 0);
            }
        }
        __syncthreads();
    }
#pragma unroll
    for (int n = 0; n < 4; ++n) {
        int c = c0 + n * 16 + (lane & 15);
        if (c < VV) {
            float bias = fc_b[c];
#pragma unroll
            for (int r = 0; r < 4; ++r) {
                int pr = p0 + w * 16 + (lane >> 4) * 4 + r;
                bool act = (t < len_ws[pr]);
                out[((size_t)pr * TT + t) * VV + c] = act ? (acc[n][r] + bias) : 0.f;
            }
        }
    }
}

// ---------------- launch ----------------
extern "C" void kernel_launch(void* const* d_in, const int* in_sizes, int n_in,
                              void* d_out, int out_size, void* d_ws, size_t ws_size,
                              hipStream_t stream) {
    const float* image_code = (const float*)d_in[0];
    const int*   captions   = (const int*)d_in[1];
    const int*   cap_lens   = (const int*)d_in[2];
    const float* embed_w    = (const float*)d_in[3];
    const float* init_w     = (const float*)d_in[4];
    const float* init_b     = (const float*)d_in[5];
    const float* w_ih0      = (const float*)d_in[6];
    const float* w_hh0      = (const float*)d_in[7];
    const float* b_ih0      = (const float*)d_in[8];
    const float* b_hh0      = (const float*)d_in[9];
    const float* w_ih1      = (const float*)d_in[10];
    const float* w_hh1      = (const float*)d_in[11];
    const float* b_ih1      = (const float*)d_in[12];
    const float* b_hh1      = (const float*)d_in[13];
    const float* fc_w       = (const float*)d_in[14];
    const float* fc_b       = (const float*)d_in[15];
    float* out = (float*)d_out;

    const size_t tail = (size_t)BB * TCAP + 2 * BB;     // 13,568
    const size_t predN = (size_t)out_size - tail;       // BB*TT*VV

    // ---- workspace ----
    char* ws = (char*)d_ws;
    int*   order_ws = (int*)(ws + 0);
    int*   len_ws   = (int*)(ws + 1024);
    int*   caps_ws  = (int*)(ws + 2048);
    unsigned short* h0s[2] = {(unsigned short*)(ws + 54272),  (unsigned short*)(ws + 316416)};
    unsigned short* h1s[2] = {(unsigned short*)(ws + 578560), (unsigned short*)(ws + 840704)};
    float* gxb[2] = {(float*)(ws + 1102848), (float*)(ws + 2675712)};
    float* gi_img   = (float*)(ws + 4248576);
    float* gi_all   = (float*)(ws + 5821440);
    unsigned short* h1x  = (unsigned short*)(ws + 84464640);
    unsigned short* fcwb = (unsigned short*)(ws + 97571840);

    // ---- bf16 staging in d_out's predictions region (consumed before fc writes) ----
    char* ob = (char*)d_out;
    unsigned short* imgb   = (unsigned short*)(ob + 0);          //  1,048,576 B
    unsigned short* wihe   = (unsigned short*)(ob + 1048576);    //  1,572,864 B
    unsigned short* wcomb  = (unsigned short*)(ob + 4194304);    // 10,485,760 B
    unsigned short* embb   = (unsigned short*)(ob + 16777216);   // 10,240,000 B
    unsigned short* whh0b  = (unsigned short*)(ob + 27262976);   //  1,572,864 B
    unsigned short* wih1b  = (unsigned short*)(ob + 29360128);   //  1,572,864 B
    unsigned short* whh1b  = (unsigned short*)(ob + 31457280);   //  1,572,864 B

    dim3 blk(256);
    hipLaunchKernelGGL(sort_kernel, dim3(1), blk, 0, stream,
                       cap_lens, captions, order_ws, len_ws, caps_ws, out, predN);
    hipLaunchKernelGGL(gather_imgb, dim3(256), blk, 0, stream, image_code, order_ws, imgb);
    hipLaunchKernelGGL(cvt_mat, dim3(1024), blk, 0, stream,
                       init_w, ICC, 0, wcomb, ICC, 0, ICC, 1024 * ICC / 8);
    hipLaunchKernelGGL(cvt_mat, dim3(1536), blk, 0, stream,
                       w_ih0, ICC + WDIM, 0, wcomb + (size_t)1024 * ICC, ICC, 0, ICC, G3H * ICC / 8);
    hipLaunchKernelGGL(cvt_mat, dim3(384), blk, 0, stream,
                       w_ih0, ICC + WDIM, ICC, wihe, WDIM, 0, WDIM, G3H * WDIM / 8);
    hipLaunchKernelGGL(cvt_mat, dim3(2500), blk, 0, stream,
                       embed_w, WDIM, 0, embb, WDIM, 0, WDIM, VV * WDIM / 8);
    hipLaunchKernelGGL(cvt_mat, dim3(2500), blk, 0, stream,
                       fc_w, WDIM, 0, fcwb, WDIM, 0, WDIM, VV * WDIM / 8);
    hipLaunchKernelGGL(cvt_mat, dim3(384), blk, 0, stream,
                       w_hh0, WDIM, 0, whh0b, WDIM, 0, WDIM, G3H * WDIM / 8);
    hipLaunchKernelGGL(cvt_mat, dim3(384), blk, 0, stream,
                       w_ih1, WDIM, 0, wih1b, WDIM, 0, WDIM, G3H * WDIM / 8);
    hipLaunchKernelGGL(cvt_mat, dim3(384), blk, 0, stream,
                       w_hh1, WDIM, 0, whh1b, WDIM, 0, WDIM, G3H * WDIM / 8);

    hipLaunchKernelGGL(gemm_front, dim3(40, 4), blk, 0, stream,
                       imgb, wcomb, init_b, b_ih0, h0s[0], h1s[0], gi_img);
    hipLaunchKernelGGL(gemm_giemb, dim3(24, 200), blk, 0, stream,
                       embb, wihe, gi_img, caps_ws, len_ws, gi_all);

    // 52 pipelined stages: stage s = { l0@s, gx1@s-1, l1h@s-2 }
    for (int s = 0; s <= TT + 1; ++s) {
        int q = s & 1;
        hipLaunchKernelGGL(gru_stage, dim3(96), blk, 0, stream, s,
                           h0s[q], h0s[q ^ 1],
                           gxb[q ^ 1], gxb[q],
                           h1s[q], h1s[q ^ 1],
                           h1x, whh0b, wih1b, whh1b,
                           b_hh0, gi_all, b_ih1, b_hh1, len_ws);
    }

    hipLaunchKernelGGL(gemm_fc_mfma, dim3(157, 200), blk, 0, stream,
                       h1x, fcwb, fc_b, len_ws, out);
}